// Round 5
// baseline (98.621 us; speedup 1.0000x reference)
//
#include <hip/hip_runtime.h>
#include <math.h>

// Problem constants (from reference)
#define N_PROP   1000
#define C_ALL    81
#define N_FG     80
#define TOPK     100
#define CAP      1024        // per-class list capacity (pow2, >= N_PROP)
#define IMG_WH   800.0f
#define SCORE_TH 0.05f
#define NMS_TH   0.5f
#define MIN_SZ   1.0f
#define BBOX_CLIP 4.135166556742356f   // log(1000/16)

typedef unsigned long long u64;

// ---------------------------------------------------------------- kernel A
// One wave per proposal row. Fully coalesced: lane l reads logit l (and
// l+64), butterfly softmax reduce, then lane l owns classes l and l+64 —
// decode+filter and push passing (class,row) entries into per-class global
// compaction lists. Only ~3-5 lanes per row pass the 0.05 softmax cut.
__global__ __launch_bounds__(256) void score_decode_kernel(
    const float* __restrict__ logits,   // [1000][81]
    const float* __restrict__ boxreg,   // [1000][324]
    const float* __restrict__ prop,     // [1000][4]
    int*    __restrict__ cnt,           // [80]   (zeroed via memset)
    u64*    __restrict__ keys,          // [80][CAP]
    float4* __restrict__ boxes)         // [80][CAP]
{
    const int wave = threadIdx.x >> 6;
    const int lane = threadIdx.x & 63;
    const int n = blockIdx.x * 4 + wave;
    if (n >= N_PROP) return;
    const float* row = logits + n * C_ALL;

    float v1 = row[lane];
    float v2 = (lane < C_ALL - 64) ? row[64 + lane] : 0.f;

    float m = (lane < C_ALL - 64) ? fmaxf(v1, v2) : v1;
    #pragma unroll
    for (int off = 32; off >= 1; off >>= 1)
        m = fmaxf(m, __shfl_xor(m, off, 64));

    float s = expf(v1 - m) + ((lane < C_ALL - 64) ? expf(v2 - m) : 0.0f);
    #pragma unroll
    for (int off = 32; off >= 1; off >>= 1)
        s += __shfl_xor(s, off, 64);

    // Proposal geometry (same address across wave -> broadcast load).
    float4 p = *(const float4*)(prop + n * 4);
    float w  = p.z - p.x;
    float h  = p.w - p.y;
    float pcx0 = p.x + 0.5f * w;
    float pcy0 = p.y + 0.5f * h;

    auto emit = [&](int col, float score) {
        if (score < SCORE_TH) return;   // invalid entries never suppress in
                                        // the reference -> safe to drop here
        float4 d = *(const float4*)(boxreg + n * (C_ALL * 4) + col * 4);
        float dx = d.x / 10.0f;
        float dy = d.y / 10.0f;
        float dw = fminf(d.z / 5.0f, BBOX_CLIP);
        float dh = fminf(d.w / 5.0f, BBOX_CLIP);

        float pcx = dx * w + pcx0;
        float pcy = dy * h + pcy0;
        float pw  = expf(dw) * w;
        float ph  = expf(dh) * h;

        float x1 = fminf(fmaxf(pcx - 0.5f * pw, 0.0f), IMG_WH);
        float y1 = fminf(fmaxf(pcy - 0.5f * ph, 0.0f), IMG_WH);
        float x2 = fminf(fmaxf(pcx + 0.5f * pw, 0.0f), IMG_WH);
        float y2 = fminf(fmaxf(pcy + 0.5f * ph, 0.0f), IMG_WH);

        if ((x2 - x1) >= MIN_SZ && (y2 - y1) >= MIN_SZ) {
            int cls = col - 1;
            int pos = atomicAdd(&cnt[cls], 1);   // pos <= 999 < CAP
            // key: (score bits | 1023-n | pos) -> descending-u64 order
            // == (score desc, row asc); n bits make keys unique per class.
            unsigned int fb = __float_as_uint(score);
            keys[cls * CAP + pos] =
                ((u64)fb << 20) | ((u64)(1023 - n) << 10) | (u64)pos;
            boxes[cls * CAP + pos] = make_float4(x1, y1, x2, y2);
        }
    };

    if (lane >= 1)              emit(lane,      expf(v1 - m) / s); // cols 1..63
    if (lane + 64 <= N_FG)      emit(lane + 64, expf(v2 - m) / s); // cols 64..80
}

// ---------------------------------------------------------------- kernel B
// One block per class: load precompacted list -> rank-sort (1 barrier) ->
// NMS (wave-resident V<=64, bit-matrix V<=256, barrier fallback).
__global__ __launch_bounds__(256) void nms_out_kernel(
    const int*    __restrict__ cnt,     // [80]
    const u64*    __restrict__ keys,    // [80][CAP]
    const float4* __restrict__ boxes,   // [80][CAP]
    float* __restrict__ out)            // 56000 floats
{
    __shared__ u64   s_key[CAP];
    __shared__ u64   s_skey[CAP];
    __shared__ float sx1[CAP], sy1[CAP], sx2[CAP], sy2[CAP], sar[CAP];
    __shared__ u64   s_mask[256 * 4];
    __shared__ u64   s_keep[4];
    __shared__ unsigned char s_rem[CAP];
    __shared__ int   s_emit;

    const int c   = blockIdx.x;
    const int tid = threadIdx.x;
    const int col = c + 1;

    const int OFF_SCORES = N_FG * TOPK * 4;          // 32000
    const int OFF_LABELS = OFF_SCORES + N_FG * TOPK; // 40000
    const int OFF_VALID  = OFF_LABELS + N_FG * TOPK; // 48000

    // Zero this class's output slice (harness poisons d_out every call).
    for (int t = tid; t < TOPK * 4; t += 256) out[c * TOPK * 4 + t] = 0.0f;
    for (int t = tid; t < TOPK; t += 256) {
        out[OFF_SCORES + c * TOPK + t] = 0.0f;
        out[OFF_LABELS + c * TOPK + t] = 0.0f;
        out[OFF_VALID  + c * TOPK + t] = 0.0f;
    }
    if (tid == 0) s_emit = 0;

    const int V = min(cnt[c], N_PROP);
    if (V == 0) { __syncthreads(); return; }

    for (int t = tid; t < V; t += 256) s_key[t] = keys[c * CAP + t];
    __syncthreads();

    // ---- rank sort (keys unique -> ranks unique; broadcast reads) -------
    for (int t = tid; t < V; t += 256) {
        u64 myk = s_key[t];
        int rank = 0;
        for (int j = 0; j < V; ++j) rank += (s_key[j] > myk) ? 1 : 0;
        s_skey[rank] = myk;
    }
    __syncthreads();

    // Gather boxes (global, L2-hot) into sorted order.
    for (int t = tid; t < V; t += 256) {
        int slot = (int)(s_skey[t] & 1023u);
        float4 b = boxes[c * CAP + slot];
        sx1[t] = b.x; sy1[t] = b.y; sx2[t] = b.z; sy2[t] = b.w;
        sar[t] = (b.z - b.x) * (b.w - b.y);
    }
    __syncthreads();

    if (V <= 64) {
        // ---- Wave-resident NMS: lane j holds sorted box j ---------------
        if (tid < 64) {
            const int lane = tid;
            bool act = lane < V;
            float bx1 = 0.f, by1 = 0.f, bx2 = 0.f, by2 = 0.f, bar = 0.f;
            if (act) {
                bx1 = sx1[lane]; by1 = sy1[lane];
                bx2 = sx2[lane]; by2 = sy2[lane];
                bar = sar[lane];
            }
            u64 myrow = 0;   // suppression row i (held by lane i)
            for (int i = 0; i < V; ++i) {
                float ix1 = __shfl(bx1, i, 64);
                float iy1 = __shfl(by1, i, 64);
                float ix2 = __shfl(bx2, i, 64);
                float iy2 = __shfl(by2, i, 64);
                float iar = __shfl(bar, i, 64);
                float lx = fmaxf(ix1, bx1);
                float ly = fmaxf(iy1, by1);
                float rx = fminf(ix2, bx2);
                float ry = fminf(iy2, by2);
                float iw = fmaxf(rx - lx, 0.0f);
                float ih = fmaxf(ry - ly, 0.0f);
                float inter = iw * ih;
                float iou = inter / (iar + bar - inter + 1e-9f);
                u64 bal = __ballot(act && (iou > NMS_TH));
                if (lane == i) {
                    u64 upper = (i == 63) ? 0ull : ~((1ull << (i + 1)) - 1ull);
                    myrow = bal & upper;        // only j > i suppressible by i
                }
            }
            u64 S = 0, K = 0;
            for (int i = 0; i < V; ++i) {
                if (!((S >> i) & 1ull)) {
                    K |= 1ull << i;
                    S |= __shfl(myrow, i, 64);
                }
            }
            // V <= 64 < TOPK: every kept box is emitted.
            if (act && ((K >> lane) & 1ull)) {
                int rank = __popcll(K & ((1ull << lane) - 1ull));
                float score = __uint_as_float((unsigned int)(s_skey[lane] >> 20));
                out[(c * TOPK + rank) * 4 + 0] = bx1;
                out[(c * TOPK + rank) * 4 + 1] = by1;
                out[(c * TOPK + rank) * 4 + 2] = bx2;
                out[(c * TOPK + rank) * 4 + 3] = by2;
                out[OFF_SCORES + c * TOPK + rank] = score;
                out[OFF_LABELS + c * TOPK + rank] = (float)col;
                out[OFF_VALID  + c * TOPK + rank] = 1.0f;
            }
        }
    } else if (V <= 256) {
        // ---- Bit-matrix NMS ---------------------------------------------
        const int BW = (V + 63) >> 6;
        for (int i = tid; i < V; i += 256) {
            float x1i = sx1[i], y1i = sy1[i], x2i = sx2[i], y2i = sy2[i];
            float ai  = sar[i];
            for (int w = 0; w < BW; ++w) {
                u64 mrow = 0;
                int j0 = w << 6;
                int j1 = min(V, j0 + 64);
                for (int j = max(j0, i + 1); j < j1; ++j) {
                    float lx = fmaxf(x1i, sx1[j]);
                    float ly = fmaxf(y1i, sy1[j]);
                    float rx = fminf(x2i, sx2[j]);
                    float ry = fminf(y2i, sy2[j]);
                    float iw = fmaxf(rx - lx, 0.0f);
                    float ih = fmaxf(ry - ly, 0.0f);
                    float inter = iw * ih;
                    float iou = inter / (ai + sar[j] - inter + 1e-9f);
                    if (iou > NMS_TH) mrow |= 1ull << (j - j0);
                }
                s_mask[(i << 2) + w] = mrow;
            }
        }
        __syncthreads();

        if (tid == 0) {
            u64 r0 = 0, r1 = 0, r2 = 0, r3 = 0;
            u64 k0 = 0, k1 = 0, k2 = 0, k3 = 0;
            int kept = 0;
            for (int i = 0; i < V; ++i) {
                int w = i >> 6;
                u64 bit = 1ull << (i & 63);
                u64 rw = (w == 0) ? r0 : (w == 1) ? r1 : (w == 2) ? r2 : r3;
                if (rw & bit) continue;
                if (w == 0) k0 |= bit; else if (w == 1) k1 |= bit;
                else if (w == 2) k2 |= bit; else k3 |= bit;
                if (++kept >= TOPK) break;
                const u64* mr = &s_mask[i << 2];
                r0 |= mr[0];
                if (BW > 1) r1 |= mr[1];
                if (BW > 2) r2 |= mr[2];
                if (BW > 3) r3 |= mr[3];
            }
            s_keep[0] = k0; s_keep[1] = k1; s_keep[2] = k2; s_keep[3] = k3;
        }
        __syncthreads();

        u64 kw0 = s_keep[0], kw1 = s_keep[1], kw2 = s_keep[2], kw3 = s_keep[3];
        for (int t = tid; t < V; t += 256) {
            int w = t >> 6;
            u64 kw = (w == 0) ? kw0 : (w == 1) ? kw1 : (w == 2) ? kw2 : kw3;
            if (!((kw >> (t & 63)) & 1ull)) continue;
            int rank = 0;
            if (w > 0) rank += __popcll(kw0);
            if (w > 1) rank += __popcll(kw1);
            if (w > 2) rank += __popcll(kw2);
            rank += __popcll(kw & ((1ull << (t & 63)) - 1ull));
            if (rank < TOPK) {
                float score = __uint_as_float((unsigned int)(s_skey[t] >> 20));
                out[(c * TOPK + rank) * 4 + 0] = sx1[t];
                out[(c * TOPK + rank) * 4 + 1] = sy1[t];
                out[(c * TOPK + rank) * 4 + 2] = sx2[t];
                out[(c * TOPK + rank) * 4 + 3] = sy2[t];
                out[OFF_SCORES + c * TOPK + rank] = score;
                out[OFF_LABELS + c * TOPK + rank] = (float)col;
                out[OFF_VALID  + c * TOPK + rank] = 1.0f;
            }
        }
    } else {
        // ---- Fallback (V > 256): barrier greedy -------------------------
        for (int t = tid; t < V; t += 256) s_rem[t] = 0;
        __syncthreads();
        for (int i = 0; i < V; ++i) {
            if (s_rem[i]) continue;
            if (tid == 0) {
                int k = s_emit;
                if (k < TOPK) {
                    float score = __uint_as_float((unsigned int)(s_skey[i] >> 20));
                    out[(c * TOPK + k) * 4 + 0] = sx1[i];
                    out[(c * TOPK + k) * 4 + 1] = sy1[i];
                    out[(c * TOPK + k) * 4 + 2] = sx2[i];
                    out[(c * TOPK + k) * 4 + 3] = sy2[i];
                    out[OFF_SCORES + c * TOPK + k] = score;
                    out[OFF_LABELS + c * TOPK + k] = (float)col;
                    out[OFF_VALID  + c * TOPK + k] = 1.0f;
                }
                s_emit = k + 1;
            }
            float x1i = sx1[i], y1i = sy1[i], x2i = sx2[i], y2i = sy2[i];
            float ai  = sar[i];
            for (int jj = i + 1 + tid; jj < V; jj += 256) {
                if (s_rem[jj]) continue;
                float lx = fmaxf(x1i, sx1[jj]);
                float ly = fmaxf(y1i, sy1[jj]);
                float rx = fminf(x2i, sx2[jj]);
                float ry = fminf(y2i, sy2[jj]);
                float iw = fmaxf(rx - lx, 0.0f);
                float ih = fmaxf(ry - ly, 0.0f);
                float inter = iw * ih;
                float iou = inter / (ai + sar[jj] - inter + 1e-9f);
                if (iou > NMS_TH) s_rem[jj] = 1;
            }
            __syncthreads();
            if (s_emit >= TOPK) break;
        }
    }
}

extern "C" void kernel_launch(void* const* d_in, const int* in_sizes, int n_in,
                              void* d_out, int out_size, void* d_ws, size_t ws_size,
                              hipStream_t stream) {
    const float* class_logit = (const float*)d_in[0];   // [1000][81]
    const float* box_reg     = (const float*)d_in[1];   // [1000][324]
    const float* proposal    = (const float*)d_in[2];   // [1000][4]
    float* out = (float*)d_out;                         // 56000 floats

    // Workspace layout (byte offsets; all 16B-aligned)
    char* ws = (char*)d_ws;
    int*    cnt   = (int*)ws;                           // 80 ints
    u64*    keys  = (u64*)(ws + 1024);                  // 80*CAP u64  (640 KB)
    float4* boxes = (float4*)(ws + 1024 + N_FG * CAP * sizeof(u64)); // 1.25 MB

    hipMemsetAsync(cnt, 0, N_FG * sizeof(int), stream);
    score_decode_kernel<<<(N_PROP + 3) / 4, 256, 0, stream>>>(
        class_logit, box_reg, proposal, cnt, keys, boxes);
    nms_out_kernel<<<N_FG, 256, 0, stream>>>(cnt, keys, boxes, out);
}

// Round 6
// 88.166 us; speedup vs baseline: 1.1186x; 1.1186x over previous
//
#include <hip/hip_runtime.h>
#include <math.h>

// Problem constants (from reference)
#define N_PROP   1000
#define C_ALL    81
#define N_FG     80
#define TOPK     100
#define CAP      1024        // max compacted entries
#define IMG_WH   800.0f
#define SCORE_TH 0.05f
#define NMS_TH   0.5f
#define MIN_SZ   1.0f
#define BBOX_CLIP 4.135166556742356f   // log(1000/16)

typedef unsigned long long u64;

// ---------------------------------------------------------------- kernel A
// One wave per proposal row: coalesced loads, butterfly shfl reduction.
// Writes (max, sum) packed as float2 for a single 8B load downstream.
__global__ __launch_bounds__(256) void softmax_stats_kernel(
    const float* __restrict__ logits,   // [1000][81]
    float2* __restrict__ stats)         // [1000] (rowmax, rowsum)
{
    const int wave = threadIdx.x >> 6;
    const int lane = threadIdx.x & 63;
    const int n = blockIdx.x * 4 + wave;
    if (n >= N_PROP) return;
    const float* row = logits + n * C_ALL;

    float v1 = row[lane];
    float v2 = (lane < C_ALL - 64) ? row[64 + lane] : 0.f;

    float m = (lane < C_ALL - 64) ? fmaxf(v1, v2) : v1;
    #pragma unroll
    for (int off = 32; off >= 1; off >>= 1)
        m = fmaxf(m, __shfl_xor(m, off, 64));

    float s = expf(v1 - m) + ((lane < C_ALL - 64) ? expf(v2 - m) : 0.0f);
    #pragma unroll
    for (int off = 32; off >= 1; off >>= 1)
        s += __shfl_xor(s, off, 64);

    if (lane == 0) stats[n] = make_float2(m, s);
}

// ---------------------------------------------------------------- kernel B
// One block per class: score -> (deferred) decode+filter+compact ->
// rank-sort (1 barrier) -> NMS (wave-resident V<=64, bit-matrix V<=256,
// barrier fallback).
__global__ __launch_bounds__(256) void roihead_kernel(
    const float* __restrict__ logits,   // [1000][81]
    const float* __restrict__ boxreg,   // [1000][324]
    const float* __restrict__ prop,     // [1000][4]
    const float2* __restrict__ stats,   // [1000]
    float* __restrict__ out)            // 56000 floats
{
    __shared__ u64   s_key[CAP];                    // compaction order
    __shared__ float cx1[CAP], cy1[CAP], cx2[CAP], cy2[CAP], car[CAP];
    __shared__ u64   s_skey[CAP];                   // sorted order
    __shared__ float sx1[CAP], sy1[CAP], sx2[CAP], sy2[CAP], sar[CAP];
    __shared__ u64   s_mask[256 * 4];
    __shared__ u64   s_keep[4];
    __shared__ unsigned char s_rem[CAP];
    __shared__ int   s_cnt, s_emit;

    const int c   = blockIdx.x;
    const int tid = threadIdx.x;
    const int col = c + 1;

    const int OFF_SCORES = N_FG * TOPK * 4;          // 32000
    const int OFF_LABELS = OFF_SCORES + N_FG * TOPK; // 40000
    const int OFF_VALID  = OFF_LABELS + N_FG * TOPK; // 48000

    // Zero this class's output slice (harness poisons d_out every call).
    for (int t = tid; t < TOPK * 4; t += 256) out[c * TOPK * 4 + t] = 0.0f;
    for (int t = tid; t < TOPK; t += 256) {
        out[OFF_SCORES + c * TOPK + t] = 0.0f;
        out[OFF_LABELS + c * TOPK + t] = 0.0f;
        out[OFF_VALID  + c * TOPK + t] = 0.0f;
    }
    if (tid == 0) { s_cnt = 0; s_emit = 0; }
    __syncthreads();

    // ---- Phase 1: score; decode only for the ~5% that pass the cut ------
    for (int n = tid; n < N_PROP; n += 256) {
        float2 ms = stats[n];
        float score = expf(logits[n * C_ALL + col] - ms.x) / ms.y;
        if (score < SCORE_TH) continue;   // reference validity requires
                                          // score >= 0.05; skip box loads

        float4 p = *(const float4*)(prop + n * 4);
        float w  = p.z - p.x;
        float h  = p.w - p.y;
        float pcx0 = p.x + 0.5f * w;
        float pcy0 = p.y + 0.5f * h;

        float4 d = *(const float4*)(boxreg + n * (C_ALL * 4) + col * 4);
        float dx = d.x / 10.0f;
        float dy = d.y / 10.0f;
        float dw = fminf(d.z / 5.0f, BBOX_CLIP);
        float dh = fminf(d.w / 5.0f, BBOX_CLIP);

        float pcx = dx * w + pcx0;
        float pcy = dy * h + pcy0;
        float pw  = expf(dw) * w;
        float ph  = expf(dh) * h;

        float x1 = fminf(fmaxf(pcx - 0.5f * pw, 0.0f), IMG_WH);
        float y1 = fminf(fmaxf(pcy - 0.5f * ph, 0.0f), IMG_WH);
        float x2 = fminf(fmaxf(pcx + 0.5f * pw, 0.0f), IMG_WH);
        float y2 = fminf(fmaxf(pcy + 0.5f * ph, 0.0f), IMG_WH);

        float bw = x2 - x1;
        float bh = y2 - y1;
        if (bw >= MIN_SZ && bh >= MIN_SZ) {
            int slot = atomicAdd(&s_cnt, 1);
            // key: (score bits | 1023-idx | slot) -> descending-u64 order
            // == (score desc, original index asc); idx bits make keys unique.
            unsigned int fb = __float_as_uint(score);
            s_key[slot] = ((u64)fb << 20) | ((u64)(1023 - n) << 10) | (u64)slot;
            cx1[slot] = x1; cy1[slot] = y1; cx2[slot] = x2; cy2[slot] = y2;
            car[slot] = bw * bh;
        }
    }
    __syncthreads();

    const int V = s_cnt;
    if (V == 0) return;                 // outputs already zeroed

    // ---- Phase 2: rank sort (keys unique -> ranks unique) ---------------
    // Inner reads are same-address across threads -> LDS broadcast.
    for (int t = tid; t < V; t += 256) {
        u64 myk = s_key[t];
        int rank = 0;
        for (int j = 0; j < V; ++j) rank += (s_key[j] > myk) ? 1 : 0;
        s_skey[rank] = myk;
        sx1[rank] = cx1[t]; sy1[rank] = cy1[t];
        sx2[rank] = cx2[t]; sy2[rank] = cy2[t];
        sar[rank] = car[t];
    }
    __syncthreads();

    if (V <= 64) {
        // ---- Wave-resident NMS: lane j holds sorted box j ---------------
        if (tid < 64) {
            const int lane = tid;
            bool act = lane < V;
            float bx1 = 0.f, by1 = 0.f, bx2 = 0.f, by2 = 0.f, bar = 0.f;
            if (act) {
                bx1 = sx1[lane]; by1 = sy1[lane];
                bx2 = sx2[lane]; by2 = sy2[lane];
                bar = sar[lane];
            }
            u64 myrow = 0;   // suppression row i (held by lane i)
            for (int i = 0; i < V; ++i) {
                float ix1 = __shfl(bx1, i, 64);
                float iy1 = __shfl(by1, i, 64);
                float ix2 = __shfl(bx2, i, 64);
                float iy2 = __shfl(by2, i, 64);
                float iar = __shfl(bar, i, 64);
                float lx = fmaxf(ix1, bx1);
                float ly = fmaxf(iy1, by1);
                float rx = fminf(ix2, bx2);
                float ry = fminf(iy2, by2);
                float iw = fmaxf(rx - lx, 0.0f);
                float ih = fmaxf(ry - ly, 0.0f);
                float inter = iw * ih;
                float iou = inter / (iar + bar - inter + 1e-9f);
                u64 bal = __ballot(act && (iou > NMS_TH));
                if (lane == i) {
                    u64 upper = (i == 63) ? 0ull : ~((1ull << (i + 1)) - 1ull);
                    myrow = bal & upper;        // only j > i suppressible by i
                }
            }
            u64 S = 0, K = 0;
            for (int i = 0; i < V; ++i) {
                if (!((S >> i) & 1ull)) {
                    K |= 1ull << i;
                    S |= __shfl(myrow, i, 64);
                }
            }
            // V <= 64 < TOPK: every kept box is emitted.
            if (act && ((K >> lane) & 1ull)) {
                int rank = __popcll(K & ((1ull << lane) - 1ull));
                float score = __uint_as_float((unsigned int)(s_skey[lane] >> 20));
                out[(c * TOPK + rank) * 4 + 0] = bx1;
                out[(c * TOPK + rank) * 4 + 1] = by1;
                out[(c * TOPK + rank) * 4 + 2] = bx2;
                out[(c * TOPK + rank) * 4 + 3] = by2;
                out[OFF_SCORES + c * TOPK + rank] = score;
                out[OFF_LABELS + c * TOPK + rank] = (float)col;
                out[OFF_VALID  + c * TOPK + rank] = 1.0f;
            }
        }
    } else if (V <= 256) {
        // ---- Bit-matrix NMS ---------------------------------------------
        const int BW = (V + 63) >> 6;
        for (int i = tid; i < V; i += 256) {
            float x1i = sx1[i], y1i = sy1[i], x2i = sx2[i], y2i = sy2[i];
            float ai  = sar[i];
            for (int w = 0; w < BW; ++w) {
                u64 mrow = 0;
                int j0 = w << 6;
                int j1 = min(V, j0 + 64);
                for (int j = max(j0, i + 1); j < j1; ++j) {
                    float lx = fmaxf(x1i, sx1[j]);
                    float ly = fmaxf(y1i, sy1[j]);
                    float rx = fminf(x2i, sx2[j]);
                    float ry = fminf(y2i, sy2[j]);
                    float iw = fmaxf(rx - lx, 0.0f);
                    float ih = fmaxf(ry - ly, 0.0f);
                    float inter = iw * ih;
                    float iou = inter / (ai + sar[j] - inter + 1e-9f);
                    if (iou > NMS_TH) mrow |= 1ull << (j - j0);
                }
                s_mask[(i << 2) + w] = mrow;
            }
        }
        __syncthreads();

        if (tid == 0) {
            u64 r0 = 0, r1 = 0, r2 = 0, r3 = 0;
            u64 k0 = 0, k1 = 0, k2 = 0, k3 = 0;
            int kept = 0;
            for (int i = 0; i < V; ++i) {
                int w = i >> 6;
                u64 bit = 1ull << (i & 63);
                u64 rw = (w == 0) ? r0 : (w == 1) ? r1 : (w == 2) ? r2 : r3;
                if (rw & bit) continue;
                if (w == 0) k0 |= bit; else if (w == 1) k1 |= bit;
                else if (w == 2) k2 |= bit; else k3 |= bit;
                if (++kept >= TOPK) break;
                const u64* mr = &s_mask[i << 2];
                r0 |= mr[0];
                if (BW > 1) r1 |= mr[1];
                if (BW > 2) r2 |= mr[2];
                if (BW > 3) r3 |= mr[3];
            }
            s_keep[0] = k0; s_keep[1] = k1; s_keep[2] = k2; s_keep[3] = k3;
        }
        __syncthreads();

        u64 kw0 = s_keep[0], kw1 = s_keep[1], kw2 = s_keep[2], kw3 = s_keep[3];
        for (int t = tid; t < V; t += 256) {
            int w = t >> 6;
            u64 kw = (w == 0) ? kw0 : (w == 1) ? kw1 : (w == 2) ? kw2 : kw3;
            if (!((kw >> (t & 63)) & 1ull)) continue;
            int rank = 0;
            if (w > 0) rank += __popcll(kw0);
            if (w > 1) rank += __popcll(kw1);
            if (w > 2) rank += __popcll(kw2);
            rank += __popcll(kw & ((1ull << (t & 63)) - 1ull));
            if (rank < TOPK) {
                float score = __uint_as_float((unsigned int)(s_skey[t] >> 20));
                out[(c * TOPK + rank) * 4 + 0] = sx1[t];
                out[(c * TOPK + rank) * 4 + 1] = sy1[t];
                out[(c * TOPK + rank) * 4 + 2] = sx2[t];
                out[(c * TOPK + rank) * 4 + 3] = sy2[t];
                out[OFF_SCORES + c * TOPK + rank] = score;
                out[OFF_LABELS + c * TOPK + rank] = (float)col;
                out[OFF_VALID  + c * TOPK + rank] = 1.0f;
            }
        }
    } else {
        // ---- Fallback (V > 256): barrier greedy -------------------------
        for (int t = tid; t < V; t += 256) s_rem[t] = 0;
        __syncthreads();
        for (int i = 0; i < V; ++i) {
            if (s_rem[i]) continue;
            if (tid == 0) {
                int k = s_emit;
                if (k < TOPK) {
                    float score = __uint_as_float((unsigned int)(s_skey[i] >> 20));
                    out[(c * TOPK + k) * 4 + 0] = sx1[i];
                    out[(c * TOPK + k) * 4 + 1] = sy1[i];
                    out[(c * TOPK + k) * 4 + 2] = sx2[i];
                    out[(c * TOPK + k) * 4 + 3] = sy2[i];
                    out[OFF_SCORES + c * TOPK + k] = score;
                    out[OFF_LABELS + c * TOPK + k] = (float)col;
                    out[OFF_VALID  + c * TOPK + k] = 1.0f;
                }
                s_emit = k + 1;
            }
            float x1i = sx1[i], y1i = sy1[i], x2i = sx2[i], y2i = sy2[i];
            float ai  = sar[i];
            for (int jj = i + 1 + tid; jj < V; jj += 256) {
                if (s_rem[jj]) continue;
                float lx = fmaxf(x1i, sx1[jj]);
                float ly = fmaxf(y1i, sy1[jj]);
                float rx = fminf(x2i, sx2[jj]);
                float ry = fminf(y2i, sy2[jj]);
                float iw = fmaxf(rx - lx, 0.0f);
                float ih = fmaxf(ry - ly, 0.0f);
                float inter = iw * ih;
                float iou = inter / (ai + sar[jj] - inter + 1e-9f);
                if (iou > NMS_TH) s_rem[jj] = 1;
            }
            __syncthreads();
            if (s_emit >= TOPK) break;
        }
    }
}

extern "C" void kernel_launch(void* const* d_in, const int* in_sizes, int n_in,
                              void* d_out, int out_size, void* d_ws, size_t ws_size,
                              hipStream_t stream) {
    const float* class_logit = (const float*)d_in[0];   // [1000][81]
    const float* box_reg     = (const float*)d_in[1];   // [1000][324]
    const float* proposal    = (const float*)d_in[2];   // [1000][4]
    float* out = (float*)d_out;                         // 56000 floats

    float2* stats = (float2*)d_ws;      // 1000 x (max, sum)

    softmax_stats_kernel<<<(N_PROP + 3) / 4, 256, 0, stream>>>(class_logit, stats);
    roihead_kernel<<<N_FG, 256, 0, stream>>>(class_logit, box_reg, proposal,
                                             stats, out);
}